// Round 15
// baseline (673.859 us; speedup 1.0000x reference)
//
#include <hip/hip_runtime.h>
#include <hip/hip_bf16.h>

#define TT 2048
#define BB 512
#define HH 32
#define CSC 2.88539008177792681f   // 2*log2(e), folded into Wx/b/Wh

// Pin a value into a live VGPR (R8/R9-proven; blocks load-sinking).
#define PIN(x) asm volatile("" : "+v"(x))

// Inputs pre-scaled by CSC => tanh(u) = 1 - 2/(1+2^u).
__device__ __forceinline__ float fast_tanh_pre(float u) {
    float e = exp2f(u);
    return fmaf(__builtin_amdgcn_rcpf(e + 1.0f), -2.0f, 1.0f);
}

// DPP row-rotate by N within each 16-lane row.
template <int N>
__device__ __forceinline__ float dpp_ror(float v) {
    return __int_as_float(__builtin_amdgcn_mov_dpp(
        __float_as_int(v), 0x120 | N, 0xF, 0xF, false));
}
// lane xor 16 within each 32-lane group (BitMode: xor=16, and=0x1F).
__device__ __forceinline__ float swz_x16(float v) {
    return __int_as_float(__builtin_amdgcn_ds_swizzle(__float_as_int(v), 0x401F));
}

// ---------------- Fused kernel: x-projection pipelined INSIDE the scan ------------------
// 256 blocks x 1 wave; lanes 0-31 = row 2b, lanes 32-63 = row 2b+1.
// Scan role (R13-exact): i=l&15, q=(l>>4)&1, lane owns h[q*16+i]; 15-DPP rotation
// stream + one ds_swizzle partial exchange + one tanh.
// Projection role: lane (r=l>>5, j=l&31) computes p[t][row][j] = CSC*(b[j]+e_t@Wx[:,j])
// as a 4-stage pipeline filling the scan's ~126 stall cyc/step:
//   S0 t: load idx(t+24)            -> idxA ring[8]
//   S1 t: gather emb[idx(t+16)][j]  -> eregs ring[8]   (coalesced 128B per half)
//   S2 t: ds_write e(t+8)           -> ebuf ring[8]    (vmcnt 8 steps old = free)
//   S3 t: matvec p(t+4) from ebuf   -> pring ring[4]   (8x broadcast ds_read_b128)
// Every stage has >=8*326 cyc of slack. No P workspace, single launch, fp32 throughout.
__global__ __launch_bounds__(64, 1) void rnn_fused(
        const int* __restrict__ x, const float* __restrict__ emb,
        const float* __restrict__ W_rnn, const float* __restrict__ b_rnn,
        const float* __restrict__ W_cls, const float* __restrict__ b_cls,
        float* __restrict__ out) {
    const int l = threadIdx.x;
    const int j = l & 31;           // projection: hidden index
    const int r = l >> 5;           // row half
    const int i = l & 15;           // scan: position in 16-lane row
    const int q = (l >> 4) & 1;     // scan: k-half
    const int row = blockIdx.x * 2 + r;

    // Direction probe (validated R6-R14: absmax 0.0).
    int rt = __builtin_amdgcn_mov_dpp(i, 0x121, 0xF, 0xF, false);
    const int d = (rt == ((i + 1) & 15)) ? 1 : -1;

    // Scan weights (CSC-folded), rotation order.
    float wKeep[16], wSend[16];
#pragma unroll
    for (int o = 0; o < 16; ++o) {
        const int k = q * 16 + ((i + d * o) & 15);
        wKeep[o] = CSC * W_rnn[(HH + k) * HH + (q * 16 + i)];
        wSend[o] = CSC * W_rnn[(HH + k) * HH + ((q ^ 1) * 16 + i)];
    }
#pragma unroll
    for (int o = 0; o < 16; ++o) { PIN(wKeep[o]); PIN(wSend[o]); }

    // Projection weights (CSC-folded): wx[k] = CSC*Wx[k][j], bias bj.
    float wx[32];
#pragma unroll
    for (int k = 0; k < 32; ++k) wx[k] = CSC * W_rnn[k * HH + j];
#pragma unroll
    for (int k = 0; k < 32; ++k) PIN(wx[k]);
    const float bj = CSC * b_rnn[j];

    __shared__ __align__(16) float ebuf[8][2][HH];   // e-row ring, 2 KB
    __shared__ float hf[64];

    auto xidx = [&](int t) -> int {
        return x[(t > TT - 1 ? TT - 1 : t) * BB + row];
    };
    auto matvec = [&](int slot) -> float {
        const float4* ep = (const float4*)&ebuf[slot][r][0];  // broadcast per half
        float a0 = bj, a1 = 0.f, a2 = 0.f, a3 = 0.f;
#pragma unroll
        for (int qq = 0; qq < 8; ++qq) {
            float4 ev = ep[qq];
            a0 = fmaf(ev.x, wx[4*qq+0], a0);
            a1 = fmaf(ev.y, wx[4*qq+1], a1);
            a2 = fmaf(ev.z, wx[4*qq+2], a2);
            a3 = fmaf(ev.w, wx[4*qq+3], a3);
        }
        return (a0 + a1) + (a2 + a3);
    };

    // ---- Prologue: prime rings. ebuf[s]=e[s] (s=0..7), pring[s]=p[s] (s=0..3),
    //      eregs[s]=e[s+8], idxA[s]=idx[s+16].
    int idxA[8];
    float eregs[8];
#pragma unroll
    for (int s = 0; s < 8; ++s)
        ebuf[s][r][j] = emb[(size_t)xidx(s) * HH + j];
    float pring[4];
#pragma unroll
    for (int s = 0; s < 4; ++s) pring[s] = matvec(s);
#pragma unroll
    for (int s = 0; s < 8; ++s)
        eregs[s] = emb[(size_t)xidx(s + 8) * HH + j];
#pragma unroll
    for (int s = 0; s < 8; ++s) PIN(eregs[s]);
#pragma unroll
    for (int s = 0; s < 8; ++s) idxA[s] = xidx(s + 16);

    float h = 0.0f;

#pragma unroll 1
    for (int e = 0; e < TT / 8; ++e) {
        const int t0 = e * 8;
#pragma unroll
        for (int s = 0; s < 8; ++s) {
            const int t = t0 + s;
            const float p = pring[s & 3];

            // ---- scan step (R13-exact) ----
            float rot[16];
            rot[0] = h;
            rot[1] = dpp_ror<1>(h);
            rot[2] = dpp_ror<2>(h);
            rot[3] = dpp_ror<3>(h);
#pragma unroll
            for (int m = 1; m < 4; ++m) {
                rot[4*m+0] = dpp_ror<4>(rot[4*m-4]);
                rot[4*m+1] = dpp_ror<4>(rot[4*m-3]);
                rot[4*m+2] = dpp_ror<4>(rot[4*m-2]);
                rot[4*m+3] = dpp_ror<4>(rot[4*m-1]);
            }
            float s0 = rot[0] * wSend[0], s1 = rot[1] * wSend[1];
            float s2 = rot[2] * wSend[2], s3 = rot[3] * wSend[3];
#pragma unroll
            for (int m = 1; m < 4; ++m) {
                s0 = fmaf(rot[4*m+0], wSend[4*m+0], s0);
                s1 = fmaf(rot[4*m+1], wSend[4*m+1], s1);
                s2 = fmaf(rot[4*m+2], wSend[4*m+2], s2);
                s3 = fmaf(rot[4*m+3], wSend[4*m+3], s3);
            }
            float send = (s0 + s1) + (s2 + s3);
            float recv = swz_x16(send);
            float k0 = fmaf(rot[0], wKeep[0], p), k1 = rot[1] * wKeep[1];
            float k2 = rot[2] * wKeep[2],         k3 = rot[3] * wKeep[3];
#pragma unroll
            for (int m = 1; m < 4; ++m) {
                k0 = fmaf(rot[4*m+0], wKeep[4*m+0], k0);
                k1 = fmaf(rot[4*m+1], wKeep[4*m+1], k1);
                k2 = fmaf(rot[4*m+2], wKeep[4*m+2], k2);
                k3 = fmaf(rot[4*m+3], wKeep[4*m+3], k3);
            }
            float u = ((k0 + k1) + (k2 + k3)) + recv;
            h = fast_tanh_pre(u);

            // ---- pipeline stages (independent of the scan chain) ----
            const int idxnew = xidx(t + 24);                     // S0
            const float enew = emb[(size_t)idxA[s] * HH + j];    // S1 (idx for t+16)
            ebuf[s][r][j] = eregs[s];                            // S2 (e for t+8)
            pring[s & 3] = matvec((s + 4) & 7);                  // S3 (p for t+4)
            idxA[s]  = idxnew;
            eregs[s] = enew;
            PIN(eregs[s]);
        }
    }

    // Epilogue: hf[l] = h lands at hf[r*32 + q*16 + i]; 10 lanes store y.
    hf[l] = h;
    if (l < 10) {
        const int rr = l / 5, c = l % 5;
        float acc = b_cls[c];
#pragma unroll
        for (int k = 0; k < 32; ++k)
            acc = fmaf(hf[rr * 32 + k], W_cls[k * 5 + c], acc);
        out[(blockIdx.x * 2 + rr) * 5 + c] = acc;
    }
}

extern "C" void kernel_launch(void* const* d_in, const int* in_sizes, int n_in,
                              void* d_out, int out_size, void* d_ws, size_t ws_size,
                              hipStream_t stream) {
    const int*   x     = (const int*)d_in[0];
    const float* emb   = (const float*)d_in[1];
    const float* W_rnn = (const float*)d_in[2];
    const float* b_rnn = (const float*)d_in[3];
    const float* W_cls = (const float*)d_in[4];
    const float* b_cls = (const float*)d_in[5];
    float* out = (float*)d_out;

    rnn_fused<<<BB / 2, 64, 0, stream>>>(x, emb, W_rnn, b_rnn, W_cls, b_cls, out);
}